// Round 5
// baseline (347.976 us; speedup 1.0000x reference)
//
#include <hip/hip_runtime.h>

// GCN layer: out = ReLU(BN(GCNConv(x) + x@skip_W))
// R5: fused gather+MFMA-GEMM per 128-node bucket; shfl-prefetched edge gather
//     (breaks csr->dinv->xb dependent-load chain); bf16 pre-BN staging.

typedef unsigned short ushort;
typedef __bf16 bf16x8 __attribute__((ext_vector_type(8)));
typedef float f32x4 __attribute__((ext_vector_type(4)));

constexpr int N_NODES = 100000;
constexpr int N_PAD   = 100096;                  // 782*128
constexpr int E_EDGES = 1600000;

constexpr int BUCK_SHIFT = 7;                    // 128 nodes per bucket
constexpr int NBUCK   = (N_NODES + 127) / 128;   // 782
constexpr int NBUCK_P = 784;
constexpr int CHUNK   = 8192;
constexpr int NCHUNK  = (E_EDGES + CHUNK - 1) / CHUNK;  // 196
constexpr int SORT_CAP = 4096;

// ws layout (4-byte element offsets)
constexpr size_t OFF_STATS  = 0;         // 256 floats (zeroed)
constexpr size_t OFF_SCALE  = 256;       // 256 floats
constexpr size_t OFF_DINV   = 512;       // N floats
constexpr size_t OFF_ROWPTR = 100608;    // N+1 ints
constexpr size_t OFF_BASE   = 200704;    // NBUCK+1 ints
constexpr size_t OFF_GHIST  = 201536;    // NCHUNK*NBUCK_P = 153664 ints
constexpr size_t OFF_BINNED = 355264;    // E ints (packed edges; csr in place)
constexpr size_t OFF_BT     = 1955264;   // 128*128 ushort
constexpr size_t OFF_XB     = 1963456;   // N_PAD*64 ushort
constexpr size_t OFF_PRE    = 5166528;   // N_PAD*128 ushort (bf16 pre-BN)
constexpr size_t WS_ZERO_BYTES = 256 * 4;  // stats only

static __device__ __forceinline__ ushort f2bf(float f) {
    union { float f; unsigned u; } v; v.f = f;
    unsigned r = v.u + 0x7FFFu + ((v.u >> 16) & 1u);  // RNE
    return (ushort)(r >> 16);
}
static __device__ __forceinline__ float bf2f(ushort u) {
    union { unsigned u; float f; } v; v.u = (unsigned)u << 16;
    return v.f;
}

// ---- Bt[n][k] = bf16(B[k][n]), B = [W; skipW] ----
__global__ void k_prep(const float* __restrict__ W, const float* __restrict__ skipW,
                       ushort* __restrict__ Bt) {
    int t = blockIdx.x * 256 + threadIdx.x;
    if (t >= 128 * 128) return;
    int k = t >> 7, n = t & 127;
    float v = (k < 64) ? W[k * 128 + n] : skipW[(k - 64) * 128 + n];
    Bt[n * 128 + k] = f2bf(v);
}

// ---- xb = bf16(x), pad rows zero ----
__global__ void k_cast(const float* __restrict__ x, ushort* __restrict__ xb) {
    int t = blockIdx.x * blockDim.x + threadIdx.x;
    if (t >= N_PAD * 16) return;
    int c = t >> 4;
    ushort4 b = {0, 0, 0, 0};
    if (c < N_NODES) {
        float4 v = ((const float4*)x)[t];
        b.x = f2bf(v.x); b.y = f2bf(v.y); b.z = f2bf(v.z); b.w = f2bf(v.w);
    }
    ((ushort4*)xb)[t] = b;
}

// ---- pass 1: per-chunk histogram over dst buckets ----
__global__ __launch_bounds__(256) void k_hist(const int* __restrict__ col,
                                              int* __restrict__ gh) {
    __shared__ int h[NBUCK_P];
    int c = blockIdx.x, t = threadIdx.x;
    for (int b = t; b < NBUCK_P; b += 256) h[b] = 0;
    __syncthreads();
    int e0 = c * CHUNK;
#pragma unroll
    for (int i = 0; i < CHUNK / 256; ++i) {
        int e = e0 + i * 256 + t;
        if (e < E_EDGES) atomicAdd(&h[col[e] >> BUCK_SHIFT], 1);
    }
    __syncthreads();
    for (int b = t; b < NBUCK_P; b += 256) gh[c * NBUCK_P + b] = h[b];
}

// ---- pass 2a: per-bucket exclusive scan over chunks; bucket totals ----
__global__ __launch_bounds__(256) void k_scan_buckets(int* __restrict__ gh,
                                                      int* __restrict__ base) {
    __shared__ int lds[256];
    int b = blockIdx.x, t = threadIdx.x;
    int v = (t < NCHUNK) ? gh[t * NBUCK_P + b] : 0;
    lds[t] = v;
    __syncthreads();
    int val = v;
#pragma unroll
    for (int off = 1; off < 256; off <<= 1) {
        int add = (t >= off) ? lds[t - off] : 0;
        __syncthreads();
        val += add;
        lds[t] = val;
        __syncthreads();
    }
    if (t < NCHUNK) gh[t * NBUCK_P + b] = val - v;
    if (t == 255) base[b] = val;
}

// ---- pass 2b: exclusive scan of bucket totals -> bucket bases ----
__global__ __launch_bounds__(1024) void k_scan_bases(int* __restrict__ base,
                                                     int* __restrict__ rowptr) {
    __shared__ int lds[1024];
    int t = threadIdx.x;
    int v = (t < NBUCK) ? base[t] : 0;
    lds[t] = v;
    __syncthreads();
    int val = v;
#pragma unroll
    for (int off = 1; off < 1024; off <<= 1) {
        int add = (t >= off) ? lds[t - off] : 0;
        __syncthreads();
        val += add;
        lds[t] = val;
        __syncthreads();
    }
    if (t < NBUCK) base[t] = val - v;
    if (t == 1023) {
        base[NBUCK] = val;
        rowptr[N_NODES] = val;
    }
}

// ---- pass 3: scatter edges into bucket-contiguous array (packed) ----
__global__ __launch_bounds__(256) void k_scatter_bin(const int* __restrict__ row,
                                                     const int* __restrict__ col,
                                                     const int* __restrict__ gh,
                                                     const int* __restrict__ base,
                                                     unsigned int* __restrict__ binned) {
    __shared__ int cur[NBUCK_P];
    int c = blockIdx.x, t = threadIdx.x;
    for (int b = t; b < NBUCK_P; b += 256) {
        int bb = (b < NBUCK) ? base[b] : 0;
        cur[b] = bb + gh[c * NBUCK_P + b];
    }
    __syncthreads();
    int e0 = c * CHUNK;
#pragma unroll
    for (int i = 0; i < CHUNK / 256; ++i) {
        int e = e0 + i * 256 + t;
        if (e < E_EDGES) {
            int d = col[e];
            int s = row[e];
            int p = atomicAdd(&cur[d >> BUCK_SHIFT], 1);
            binned[p] = ((unsigned int)(d & 127) << 17) | (unsigned int)s;
        }
    }
}

// ---- pass 4: per-bucket in-LDS counting sort -> csr, rowptr, dinv ----
__global__ __launch_bounds__(256) void k_sortbucket(unsigned int* __restrict__ binned,
                                                    const int* __restrict__ base,
                                                    int* __restrict__ rowptr,
                                                    float* __restrict__ dinv) {
    __shared__ unsigned int ebuf[SORT_CAP];
    __shared__ int sbuf[SORT_CAP];
    __shared__ int lcnt[128];
    __shared__ int scanb[128];
    __shared__ int lptr[128];
    int b = blockIdx.x, t = threadIdx.x;
    int i0 = base[b], i1 = base[b + 1];
    int cnt = i1 - i0;
    if (cnt > SORT_CAP) cnt = SORT_CAP;
    int n0 = b << BUCK_SHIFT;
    int nn = min(128, N_NODES - n0);

    for (int k = t; k < cnt; k += 256) ebuf[k] = binned[i0 + k];
    if (t < 128) lcnt[t] = 0;
    __syncthreads();
    for (int k = t; k < cnt; k += 256) atomicAdd(&lcnt[ebuf[k] >> 17], 1);
    __syncthreads();

    int myc = (t < 128) ? lcnt[t] : 0;
    if (t < 128) scanb[t] = myc;
    __syncthreads();
    int val = myc;
#pragma unroll
    for (int off = 1; off < 128; off <<= 1) {
        int add = (t < 128 && t >= off) ? scanb[t - off] : 0;
        __syncthreads();
        if (t < 128) {
            val += add;
            scanb[t] = val;
        }
        __syncthreads();
    }
    if (t < 128) {
        int excl = val - myc;
        lptr[t] = excl;
        if (t < nn) {
            rowptr[n0 + t] = i0 + excl;
            dinv[n0 + t] = rsqrtf((float)myc + 1.0f);  // +1 self loop
        }
    }
    __syncthreads();
    for (int k = t; k < cnt; k += 256) {
        unsigned int e = ebuf[k];
        int j = (int)(e >> 17);
        int p = atomicAdd(&lptr[j], 1);
        sbuf[p] = (int)(e & 0x1FFFF);
    }
    __syncthreads();
    for (int k = t; k < cnt; k += 256) binned[i0 + k] = (unsigned int)sbuf[k];
}

// ---- fused: gather-aggregate (shfl-prefetch) + MFMA GEMM per 128-node bucket ----
// phase 1: u[c] = dinv[c]*(x[c]*dinv[c] + sum x[r]*dinv[r]) -> LDS (bf16);
//          self x rows -> LDS.
// phase 2: pre = [u|x] @ Bt^T + bias (MFMA), stats; store bf16.
constexpr int LDP = 72;  // padded row length (ushort) -> 2-way-free LDS banks
__global__ __launch_bounds__(256) void k_agg_gemm(
    const ushort* __restrict__ xb, const float* __restrict__ dinv,
    const int* __restrict__ rowptr, const unsigned int* __restrict__ csr,
    const ushort* __restrict__ Bt, const float* __restrict__ bias,
    ushort* __restrict__ pre, float* __restrict__ stats) {
    __shared__ ushort us[128][LDP];
    __shared__ ushort xs[128][LDP];
    __shared__ float sred[128];
    __shared__ float qred[128];

    int tid = threadIdx.x;
    int n0 = blockIdx.x << BUCK_SHIFT;
    int lane = tid & 63;
    int g = tid >> 4;        // 16 groups of 16 lanes
    int q = tid & 15;
    int gbase = lane & 48;   // group base lane within wave

    if (tid < 128) { sred[tid] = 0.f; qred[tid] = 0.f; }

    // ---- phase 1 ----
    for (int it = 0; it < 8; ++it) {
        int nl = g * 8 + it;
        int c = n0 + nl;
        float4 acc = make_float4(0.f, 0.f, 0.f, 0.f);
        ushort4 xv = {0, 0, 0, 0};
        if (c < N_NODES) {
            float dc = dinv[c];
            xv = ((const ushort4*)xb)[c * 16 + q];
            acc.x = bf2f(xv.x) * dc; acc.y = bf2f(xv.y) * dc;
            acc.z = bf2f(xv.z) * dc; acc.w = bf2f(xv.w) * dc;
            int i0 = rowptr[c], i1 = rowptr[c + 1];
            for (int base = i0; base < i1; base += 16) {
                int rem = i1 - base;
                int m = rem < 16 ? rem : 16;
                int ii = base + (q < rem ? q : 0);
                int sp = (int)csr[ii];
                float dp = dinv[sp];
                for (int j = 0; j < m; ++j) {
                    int s = __shfl(sp, gbase + j);
                    float ds = __shfl(dp, gbase + j);
                    ushort4 v = ((const ushort4*)xb)[s * 16 + q];
                    acc.x += bf2f(v.x) * ds; acc.y += bf2f(v.y) * ds;
                    acc.z += bf2f(v.z) * ds; acc.w += bf2f(v.w) * ds;
                }
            }
            acc.x *= dc; acc.y *= dc; acc.z *= dc; acc.w *= dc;
        }
        ushort4 o;
        o.x = f2bf(acc.x); o.y = f2bf(acc.y); o.z = f2bf(acc.z); o.w = f2bf(acc.w);
        *(ushort4*)&us[nl][q * 4] = o;
        *(ushort4*)&xs[nl][q * 4] = xv;
    }
    __syncthreads();

    // ---- phase 2: MFMA ----
    int wave = tid >> 6;
    int wm = wave >> 1, wn = wave & 1;
    int l15 = lane & 15, quad = lane >> 4;
    int row0 = wm * 64;           // block-local
    int col0 = wn * 64;

    f32x4 acc[4][4];
#pragma unroll
    for (int a = 0; a < 4; ++a)
#pragma unroll
        for (int b = 0; b < 4; ++b) acc[a][b] = (f32x4){0.f, 0.f, 0.f, 0.f};

#pragma unroll
    for (int kc = 0; kc < 4; ++kc) {
        const ushort* abase = (kc < 2) ? &us[0][0] : &xs[0][0];
        int ko = (kc & 1) * 32 + quad * 8;
        bf16x8 a[4], b[4];
#pragma unroll
        for (int im = 0; im < 4; ++im)
            a[im] = *(const bf16x8*)&abase[(row0 + im * 16 + l15) * LDP + ko];
#pragma unroll
        for (int jn = 0; jn < 4; ++jn)
            b[jn] = *(const bf16x8*)&Bt[(size_t)(col0 + jn * 16 + l15) * 128 + kc * 32 + quad * 8];
#pragma unroll
        for (int im = 0; im < 4; ++im)
#pragma unroll
            for (int jn = 0; jn < 4; ++jn)
                acc[im][jn] = __builtin_amdgcn_mfma_f32_16x16x32_bf16(
                    a[im], b[jn], acc[im][jn], 0, 0, 0);
    }

    // epilogue: +bias, store bf16 pre, column stats
    int coln[4];
    float bi[4];
#pragma unroll
    for (int jn = 0; jn < 4; ++jn) {
        coln[jn] = col0 + jn * 16 + l15;
        bi[jn] = bias[coln[jn]];
    }
    float lsum[4] = {0.f, 0.f, 0.f, 0.f};
    float lsq[4]  = {0.f, 0.f, 0.f, 0.f};
#pragma unroll
    for (int im = 0; im < 4; ++im) {
        int rbase = row0 + im * 16 + quad * 4;
#pragma unroll
        for (int r = 0; r < 4; ++r) {
            int rowi = n0 + rbase + r;
            if (rowi < N_NODES) {
#pragma unroll
                for (int jn = 0; jn < 4; ++jn) {
                    float v = acc[im][jn][r] + bi[jn];
                    pre[(size_t)rowi * 128 + coln[jn]] = f2bf(v);
                    lsum[jn] += v;
                    lsq[jn]  += v * v;
                }
            }
        }
    }
#pragma unroll
    for (int jn = 0; jn < 4; ++jn) {
        atomicAdd(&sred[coln[jn]], lsum[jn]);
        atomicAdd(&qred[coln[jn]], lsq[jn]);
    }
    __syncthreads();
    if (tid < 128) {
        atomicAdd(&stats[tid], sred[tid]);
        atomicAdd(&stats[128 + tid], qred[tid]);
    }
}

__global__ void k_finalize(const float* __restrict__ stats,
                           const float* __restrict__ gamma,
                           const float* __restrict__ beta,
                           float* __restrict__ scaleshift) {
    int j = threadIdx.x;
    if (j < 128) {
        float mean = stats[j] * (1.0f / N_NODES);
        float var  = stats[128 + j] * (1.0f / N_NODES) - mean * mean;
        float sc   = gamma[j] * rsqrtf(var + 1e-5f);
        scaleshift[j]       = sc;
        scaleshift[128 + j] = beta[j] - mean * sc;
    }
}

// read bf16 pre, write fp32 out
__global__ void k_apply(const ushort* __restrict__ pre, float* __restrict__ out,
                        const float* __restrict__ scaleshift) {
    int t = blockIdx.x * blockDim.x + threadIdx.x;
    if (t >= N_NODES * 32) return;
    int j4 = t & 31;
    ushort4 p = ((const ushort4*)pre)[t];
    float4 sc = ((const float4*)scaleshift)[j4];
    float4 sh = ((const float4*)(scaleshift + 128))[j4];
    float4 v;
    v.x = fmaxf(fmaf(bf2f(p.x), sc.x, sh.x), 0.f);
    v.y = fmaxf(fmaf(bf2f(p.y), sc.y, sh.y), 0.f);
    v.z = fmaxf(fmaf(bf2f(p.z), sc.z, sh.z), 0.f);
    v.w = fmaxf(fmaf(bf2f(p.w), sc.w, sh.w), 0.f);
    ((float4*)out)[t] = v;
}

extern "C" void kernel_launch(void* const* d_in, const int* in_sizes, int n_in,
                              void* d_out, int out_size, void* d_ws, size_t ws_size,
                              hipStream_t stream) {
    const float* x      = (const float*)d_in[0];
    const int*   eidx   = (const int*)d_in[1];
    const float* W      = (const float*)d_in[2];
    const float* bias   = (const float*)d_in[3];
    const float* skipW  = (const float*)d_in[4];
    const float* gamma  = (const float*)d_in[5];
    const float* beta   = (const float*)d_in[6];
    float* out = (float*)d_out;
    float* ws  = (float*)d_ws;

    const int* row = eidx;
    const int* col = eidx + E_EDGES;

    float* stats      = ws + OFF_STATS;
    float* scaleshift = ws + OFF_SCALE;
    float* dinv       = ws + OFF_DINV;
    int*   rowptr     = (int*)(ws + OFF_ROWPTR);
    int*   base       = (int*)(ws + OFF_BASE);
    int*   gh         = (int*)(ws + OFF_GHIST);
    unsigned int* binned = (unsigned int*)(ws + OFF_BINNED);
    ushort* Bt        = (ushort*)(ws + OFF_BT);
    ushort* xb        = (ushort*)(ws + OFF_XB);
    ushort* pre       = (ushort*)(ws + OFF_PRE);

    hipMemsetAsync(d_ws, 0, WS_ZERO_BYTES, stream);

    k_prep<<<64, 256, 0, stream>>>(W, skipW, Bt);
    k_cast<<<(N_PAD * 16 + 255) / 256, 256, 0, stream>>>(x, xb);
    k_hist<<<NCHUNK, 256, 0, stream>>>(col, gh);
    k_scan_buckets<<<NBUCK, 256, 0, stream>>>(gh, base);
    k_scan_bases<<<1, 1024, 0, stream>>>(base, rowptr);
    k_scatter_bin<<<NCHUNK, 256, 0, stream>>>(row, col, gh, base, binned);
    k_sortbucket<<<NBUCK, 256, 0, stream>>>(binned, base, rowptr, dinv);
    k_agg_gemm<<<NBUCK, 256, 0, stream>>>(xb, dinv, rowptr, binned, Bt, bias, pre, stats);
    k_finalize<<<1, 128, 0, stream>>>(stats, gamma, beta, scaleshift);
    k_apply<<<(N_NODES * 32 + 255) / 256, 256, 0, stream>>>(pre, out, scaleshift);
}

// Round 6
// 267.022 us; speedup vs baseline: 1.3032x; 1.3032x over previous
//
#include <hip/hip_runtime.h>

// GCN layer: out = ReLU(BN(GCNConv(x) + x@skip_W))
// R6: split structure (R5 fusion regressed: occupancy collapse). Gather uses
//     premultiplied xd = bf16(x*dinv) (2-load chain) + unroll-4 batched loads.
//     CHUNK 4096 for build parallelism. bf16 pre-BN staging.

typedef unsigned short ushort;
typedef __bf16 bf16x8 __attribute__((ext_vector_type(8)));
typedef float f32x4 __attribute__((ext_vector_type(4)));

constexpr int N_NODES = 100000;
constexpr int N_PAD   = 100096;                  // 782*128
constexpr int E_EDGES = 1600000;

constexpr int BUCK_SHIFT = 7;                    // 128 nodes per bucket
constexpr int NBUCK   = (N_NODES + 127) / 128;   // 782
constexpr int NBUCK_P = 784;
constexpr int CHUNK   = 4096;
constexpr int NCHUNK  = (E_EDGES + CHUNK - 1) / CHUNK;  // 391
constexpr int SORT_CAP = 4096;

// ws layout (4-byte element offsets)
constexpr size_t OFF_STATS  = 0;         // 256 floats (zeroed)
constexpr size_t OFF_SCALE  = 256;       // 256 floats
constexpr size_t OFF_DINV   = 512;       // N_PAD floats
constexpr size_t OFF_ROWPTR = 100608;    // N+1 ints (pad 100128)
constexpr size_t OFF_BASE   = 200736;    // NBUCK+1 ints (pad 800)
constexpr size_t OFF_GHIST  = 201536;    // NCHUNK*NBUCK_P = 306544 ints
constexpr size_t OFF_BINNED = 508080;    // E ints (packed edges; csr in place)
constexpr size_t OFF_XB     = 2108080;   // N_PAD*64 ushort = 3203072 floats
constexpr size_t OFF_U      = 5311152;   // N_PAD*64 ushort
constexpr size_t OFF_PRE    = 8514224;   // N_PAD*128 ushort (bf16 pre-BN)
constexpr size_t OFF_XD     = OFF_PRE;   // xd aliases pre (dead before k_gemm)
constexpr size_t OFF_BT     = 8514224 + 6406144;  // 128*128 ushort = 8192 floats
constexpr size_t WS_ZERO_BYTES = 256 * 4;  // stats only

static __device__ __forceinline__ ushort f2bf(float f) {
    union { float f; unsigned u; } v; v.f = f;
    unsigned r = v.u + 0x7FFFu + ((v.u >> 16) & 1u);  // RNE
    return (ushort)(r >> 16);
}
static __device__ __forceinline__ float bf2f(ushort u) {
    union { unsigned u; float f; } v; v.u = (unsigned)u << 16;
    return v.f;
}

// ---- Bt[n][k] = bf16(B[k][n]), B = [W; skipW] ----
__global__ void k_prep(const float* __restrict__ W, const float* __restrict__ skipW,
                       ushort* __restrict__ Bt) {
    int t = blockIdx.x * 256 + threadIdx.x;
    if (t >= 128 * 128) return;
    int k = t >> 7, n = t & 127;
    float v = (k < 64) ? W[k * 128 + n] : skipW[(k - 64) * 128 + n];
    Bt[n * 128 + k] = f2bf(v);
}

// ---- xb = bf16(x), pad rows zero ----
__global__ void k_cast(const float* __restrict__ x, ushort* __restrict__ xb) {
    int t = blockIdx.x * blockDim.x + threadIdx.x;
    if (t >= N_PAD * 16) return;
    int c = t >> 4;
    ushort4 b = {0, 0, 0, 0};
    if (c < N_NODES) {
        float4 v = ((const float4*)x)[t];
        b.x = f2bf(v.x); b.y = f2bf(v.y); b.z = f2bf(v.z); b.w = f2bf(v.w);
    }
    ((ushort4*)xb)[t] = b;
}

// ---- xd = bf16(x * dinv[row]) (needs dinv; runs after sort) ----
__global__ void k_scale(const ushort* __restrict__ xb, const float* __restrict__ dinv,
                        ushort* __restrict__ xd) {
    int t = blockIdx.x * blockDim.x + threadIdx.x;
    if (t >= N_PAD * 16) return;
    int c = t >> 4;
    ushort4 o = {0, 0, 0, 0};
    if (c < N_NODES) {
        float d = dinv[c];
        ushort4 v = ((const ushort4*)xb)[t];
        o.x = f2bf(bf2f(v.x) * d); o.y = f2bf(bf2f(v.y) * d);
        o.z = f2bf(bf2f(v.z) * d); o.w = f2bf(bf2f(v.w) * d);
    }
    ((ushort4*)xd)[t] = o;
}

// ---- pass 1: per-chunk histogram over dst buckets ----
__global__ __launch_bounds__(256) void k_hist(const int* __restrict__ col,
                                              int* __restrict__ gh) {
    __shared__ int h[NBUCK_P];
    int c = blockIdx.x, t = threadIdx.x;
    for (int b = t; b < NBUCK_P; b += 256) h[b] = 0;
    __syncthreads();
    int e0 = c * CHUNK;
#pragma unroll
    for (int i = 0; i < CHUNK / 256; ++i) {
        int e = e0 + i * 256 + t;
        if (e < E_EDGES) atomicAdd(&h[col[e] >> BUCK_SHIFT], 1);
    }
    __syncthreads();
    for (int b = t; b < NBUCK_P; b += 256) gh[c * NBUCK_P + b] = h[b];
}

// ---- pass 2a: per-bucket exclusive scan over chunks; bucket totals ----
__global__ __launch_bounds__(512) void k_scan_buckets(int* __restrict__ gh,
                                                      int* __restrict__ base) {
    __shared__ int lds[512];
    int b = blockIdx.x, t = threadIdx.x;
    int v = (t < NCHUNK) ? gh[t * NBUCK_P + b] : 0;
    lds[t] = v;
    __syncthreads();
    int val = v;
#pragma unroll
    for (int off = 1; off < 512; off <<= 1) {
        int add = (t >= off) ? lds[t - off] : 0;
        __syncthreads();
        val += add;
        lds[t] = val;
        __syncthreads();
    }
    if (t < NCHUNK) gh[t * NBUCK_P + b] = val - v;
    if (t == 511) base[b] = val;
}

// ---- pass 2b: exclusive scan of bucket totals -> bucket bases ----
__global__ __launch_bounds__(1024) void k_scan_bases(int* __restrict__ base,
                                                     int* __restrict__ rowptr) {
    __shared__ int lds[1024];
    int t = threadIdx.x;
    int v = (t < NBUCK) ? base[t] : 0;
    lds[t] = v;
    __syncthreads();
    int val = v;
#pragma unroll
    for (int off = 1; off < 1024; off <<= 1) {
        int add = (t >= off) ? lds[t - off] : 0;
        __syncthreads();
        val += add;
        lds[t] = val;
        __syncthreads();
    }
    if (t < NBUCK) base[t] = val - v;
    if (t == 1023) {
        base[NBUCK] = val;
        rowptr[N_NODES] = val;
    }
}

// ---- pass 3: scatter edges into bucket-contiguous array (packed) ----
__global__ __launch_bounds__(256) void k_scatter_bin(const int* __restrict__ row,
                                                     const int* __restrict__ col,
                                                     const int* __restrict__ gh,
                                                     const int* __restrict__ base,
                                                     unsigned int* __restrict__ binned) {
    __shared__ int cur[NBUCK_P];
    int c = blockIdx.x, t = threadIdx.x;
    for (int b = t; b < NBUCK_P; b += 256) {
        int bb = (b < NBUCK) ? base[b] : 0;
        cur[b] = bb + gh[c * NBUCK_P + b];
    }
    __syncthreads();
    int e0 = c * CHUNK;
#pragma unroll
    for (int i = 0; i < CHUNK / 256; ++i) {
        int e = e0 + i * 256 + t;
        if (e < E_EDGES) {
            int d = col[e];
            int s = row[e];
            int p = atomicAdd(&cur[d >> BUCK_SHIFT], 1);
            binned[p] = ((unsigned int)(d & 127) << 17) | (unsigned int)s;
        }
    }
}

// ---- pass 4: per-bucket in-LDS counting sort -> csr, rowptr, dinv ----
__global__ __launch_bounds__(256) void k_sortbucket(unsigned int* __restrict__ binned,
                                                    const int* __restrict__ base,
                                                    int* __restrict__ rowptr,
                                                    float* __restrict__ dinv) {
    __shared__ unsigned int ebuf[SORT_CAP];
    __shared__ int sbuf[SORT_CAP];
    __shared__ int lcnt[128];
    __shared__ int scanb[128];
    __shared__ int lptr[128];
    int b = blockIdx.x, t = threadIdx.x;
    int i0 = base[b], i1 = base[b + 1];
    int cnt = i1 - i0;
    if (cnt > SORT_CAP) cnt = SORT_CAP;
    int n0 = b << BUCK_SHIFT;
    int nn = min(128, N_NODES - n0);

    for (int k = t; k < cnt; k += 256) ebuf[k] = binned[i0 + k];
    if (t < 128) lcnt[t] = 0;
    __syncthreads();
    for (int k = t; k < cnt; k += 256) atomicAdd(&lcnt[ebuf[k] >> 17], 1);
    __syncthreads();

    int myc = (t < 128) ? lcnt[t] : 0;
    if (t < 128) scanb[t] = myc;
    __syncthreads();
    int val = myc;
#pragma unroll
    for (int off = 1; off < 128; off <<= 1) {
        int add = (t < 128 && t >= off) ? scanb[t - off] : 0;
        __syncthreads();
        if (t < 128) {
            val += add;
            scanb[t] = val;
        }
        __syncthreads();
    }
    if (t < 128) {
        int excl = val - myc;
        lptr[t] = excl;
        if (t < nn) {
            rowptr[n0 + t] = i0 + excl;
            dinv[n0 + t] = rsqrtf((float)myc + 1.0f);  // +1 self loop
        }
    }
    __syncthreads();
    for (int k = t; k < cnt; k += 256) {
        unsigned int e = ebuf[k];
        int j = (int)(e >> 17);
        int p = atomicAdd(&lptr[j], 1);
        sbuf[p] = (int)(e & 0x1FFFF);
    }
    __syncthreads();
    for (int k = t; k < cnt; k += 256) binned[i0 + k] = (unsigned int)sbuf[k];
}

// ---- aggregation: 16 lanes per node; unroll-4 batched independent gathers ----
// u[c] = bf16( dinv[c] * ( xd[c] + sum_{r->c} xd[r] ) ),  xd = x*dinv
__global__ __launch_bounds__(256) void k_agg(const ushort* __restrict__ xd,
                                             const float* __restrict__ dinv,
                                             const int* __restrict__ rowptr,
                                             const unsigned int* __restrict__ csr,
                                             ushort* __restrict__ u) {
    int t = blockIdx.x * blockDim.x + threadIdx.x;
    if (t >= N_PAD * 16) return;
    int c = t >> 4;
    int q = t & 15;
    if (c >= N_NODES) {
        ushort4 z = {0, 0, 0, 0};
        ((ushort4*)u)[t] = z;
        return;
    }
    float dc = dinv[c];
    ushort4 xv = ((const ushort4*)xd)[t];
    float4 acc;
    acc.x = bf2f(xv.x); acc.y = bf2f(xv.y);
    acc.z = bf2f(xv.z); acc.w = bf2f(xv.w);
    int i0 = rowptr[c], i1 = rowptr[c + 1];
    int i = i0;
    for (; i + 4 <= i1; i += 4) {
        int s0 = (int)csr[i];
        int s1 = (int)csr[i + 1];
        int s2 = (int)csr[i + 2];
        int s3 = (int)csr[i + 3];
        ushort4 v0 = ((const ushort4*)xd)[s0 * 16 + q];
        ushort4 v1 = ((const ushort4*)xd)[s1 * 16 + q];
        ushort4 v2 = ((const ushort4*)xd)[s2 * 16 + q];
        ushort4 v3 = ((const ushort4*)xd)[s3 * 16 + q];
        acc.x += bf2f(v0.x) + bf2f(v1.x) + bf2f(v2.x) + bf2f(v3.x);
        acc.y += bf2f(v0.y) + bf2f(v1.y) + bf2f(v2.y) + bf2f(v3.y);
        acc.z += bf2f(v0.z) + bf2f(v1.z) + bf2f(v2.z) + bf2f(v3.z);
        acc.w += bf2f(v0.w) + bf2f(v1.w) + bf2f(v2.w) + bf2f(v3.w);
    }
    for (; i < i1; ++i) {
        int s = (int)csr[i];
        ushort4 v = ((const ushort4*)xd)[s * 16 + q];
        acc.x += bf2f(v.x); acc.y += bf2f(v.y);
        acc.z += bf2f(v.z); acc.w += bf2f(v.w);
    }
    ushort4 o;
    o.x = f2bf(acc.x * dc); o.y = f2bf(acc.y * dc);
    o.z = f2bf(acc.z * dc); o.w = f2bf(acc.w * dc);
    ((ushort4*)u)[t] = o;
}

// ---- MFMA GEMM: pre = [u|xb] @ Bt^T + bias (bf16 out); per-column stats ----
// LDS-free frags; block = 4 waves = 128 rows; wave 64x64 (4x4 of 16x16x32).
__global__ __launch_bounds__(256) void k_gemm(const ushort* __restrict__ u,
                                              const ushort* __restrict__ xb,
                                              const ushort* __restrict__ Bt,
                                              const float* __restrict__ bias,
                                              ushort* __restrict__ pre,
                                              float* __restrict__ stats) {
    __shared__ float sred[128];
    __shared__ float qred[128];
    int tid = threadIdx.x;
    int wave = tid >> 6, lane = tid & 63;
    int wm = wave >> 1, wn = wave & 1;
    int l15 = lane & 15, quad = lane >> 4;
    int row0 = blockIdx.x * 128 + wm * 64;
    int col0 = wn * 64;

    if (tid < 128) { sred[tid] = 0.f; qred[tid] = 0.f; }
    __syncthreads();

    f32x4 acc[4][4];
#pragma unroll
    for (int a = 0; a < 4; ++a)
#pragma unroll
        for (int b = 0; b < 4; ++b) acc[a][b] = (f32x4){0.f, 0.f, 0.f, 0.f};

#pragma unroll
    for (int kc = 0; kc < 4; ++kc) {
        const ushort* abase = (kc < 2) ? u : xb;
        int ko = (kc & 1) * 32 + quad * 8;
        bf16x8 a[4], b[4];
#pragma unroll
        for (int im = 0; im < 4; ++im)
            a[im] = *(const bf16x8*)&abase[(size_t)(row0 + im * 16 + l15) * 64 + ko];
#pragma unroll
        for (int jn = 0; jn < 4; ++jn)
            b[jn] = *(const bf16x8*)&Bt[(size_t)(col0 + jn * 16 + l15) * 128 + kc * 32 + quad * 8];
#pragma unroll
        for (int im = 0; im < 4; ++im)
#pragma unroll
            for (int jn = 0; jn < 4; ++jn)
                acc[im][jn] = __builtin_amdgcn_mfma_f32_16x16x32_bf16(
                    a[im], b[jn], acc[im][jn], 0, 0, 0);
    }

    int coln[4];
    float bi[4];
#pragma unroll
    for (int jn = 0; jn < 4; ++jn) {
        coln[jn] = col0 + jn * 16 + l15;
        bi[jn] = bias[coln[jn]];
    }
    float lsum[4] = {0.f, 0.f, 0.f, 0.f};
    float lsq[4]  = {0.f, 0.f, 0.f, 0.f};
#pragma unroll
    for (int im = 0; im < 4; ++im) {
        int rbase = row0 + im * 16 + quad * 4;
#pragma unroll
        for (int r = 0; r < 4; ++r) {
            int rowi = rbase + r;
            if (rowi < N_NODES) {
#pragma unroll
                for (int jn = 0; jn < 4; ++jn) {
                    float v = acc[im][jn][r] + bi[jn];
                    pre[(size_t)rowi * 128 + coln[jn]] = f2bf(v);
                    lsum[jn] += v;
                    lsq[jn]  += v * v;
                }
            }
        }
    }
#pragma unroll
    for (int jn = 0; jn < 4; ++jn) {
        atomicAdd(&sred[coln[jn]], lsum[jn]);
        atomicAdd(&qred[coln[jn]], lsq[jn]);
    }
    __syncthreads();
    if (tid < 128) {
        atomicAdd(&stats[tid], sred[tid]);
        atomicAdd(&stats[128 + tid], qred[tid]);
    }
}

__global__ void k_finalize(const float* __restrict__ stats,
                           const float* __restrict__ gamma,
                           const float* __restrict__ beta,
                           float* __restrict__ scaleshift) {
    int j = threadIdx.x;
    if (j < 128) {
        float mean = stats[j] * (1.0f / N_NODES);
        float var  = stats[128 + j] * (1.0f / N_NODES) - mean * mean;
        float sc   = gamma[j] * rsqrtf(var + 1e-5f);
        scaleshift[j]       = sc;
        scaleshift[128 + j] = beta[j] - mean * sc;
    }
}

// read bf16 pre, write fp32 out
__global__ void k_apply(const ushort* __restrict__ pre, float* __restrict__ out,
                        const float* __restrict__ scaleshift) {
    int t = blockIdx.x * blockDim.x + threadIdx.x;
    if (t >= N_NODES * 32) return;
    int j4 = t & 31;
    ushort4 p = ((const ushort4*)pre)[t];
    float4 sc = ((const float4*)scaleshift)[j4];
    float4 sh = ((const float4*)(scaleshift + 128))[j4];
    float4 v;
    v.x = fmaxf(fmaf(bf2f(p.x), sc.x, sh.x), 0.f);
    v.y = fmaxf(fmaf(bf2f(p.y), sc.y, sh.y), 0.f);
    v.z = fmaxf(fmaf(bf2f(p.z), sc.z, sh.z), 0.f);
    v.w = fmaxf(fmaf(bf2f(p.w), sc.w, sh.w), 0.f);
    ((float4*)out)[t] = v;
}

extern "C" void kernel_launch(void* const* d_in, const int* in_sizes, int n_in,
                              void* d_out, int out_size, void* d_ws, size_t ws_size,
                              hipStream_t stream) {
    const float* x      = (const float*)d_in[0];
    const int*   eidx   = (const int*)d_in[1];
    const float* W      = (const float*)d_in[2];
    const float* bias   = (const float*)d_in[3];
    const float* skipW  = (const float*)d_in[4];
    const float* gamma  = (const float*)d_in[5];
    const float* beta   = (const float*)d_in[6];
    float* out = (float*)d_out;
    float* ws  = (float*)d_ws;

    const int* row = eidx;
    const int* col = eidx + E_EDGES;

    float* stats      = ws + OFF_STATS;
    float* scaleshift = ws + OFF_SCALE;
    float* dinv       = ws + OFF_DINV;
    int*   rowptr     = (int*)(ws + OFF_ROWPTR);
    int*   base       = (int*)(ws + OFF_BASE);
    int*   gh         = (int*)(ws + OFF_GHIST);
    unsigned int* binned = (unsigned int*)(ws + OFF_BINNED);
    ushort* xb        = (ushort*)(ws + OFF_XB);
    ushort* u         = (ushort*)(ws + OFF_U);
    ushort* xd        = (ushort*)(ws + OFF_XD);   // aliases pre (dead by k_gemm)
    ushort* pre       = (ushort*)(ws + OFF_PRE);
    ushort* Bt        = (ushort*)(ws + OFF_BT);

    hipMemsetAsync(d_ws, 0, WS_ZERO_BYTES, stream);

    k_prep<<<64, 256, 0, stream>>>(W, skipW, Bt);
    k_cast<<<(N_PAD * 16 + 255) / 256, 256, 0, stream>>>(x, xb);
    k_hist<<<NCHUNK, 256, 0, stream>>>(col, gh);
    k_scan_buckets<<<NBUCK, 512, 0, stream>>>(gh, base);
    k_scan_bases<<<1, 1024, 0, stream>>>(base, rowptr);
    k_scatter_bin<<<NCHUNK, 256, 0, stream>>>(row, col, gh, base, binned);
    k_sortbucket<<<NBUCK, 256, 0, stream>>>(binned, base, rowptr, dinv);
    k_scale<<<(N_PAD * 16 + 255) / 256, 256, 0, stream>>>(xb, dinv, xd);
    k_agg<<<(N_PAD * 16 + 255) / 256, 256, 0, stream>>>(xd, dinv, rowptr, binned, u);
    k_gemm<<<NBUCK, 256, 0, stream>>>(u, xb, Bt, bias, pre, stats);
    k_finalize<<<1, 128, 0, stream>>>(stats, gamma, beta, scaleshift);
    k_apply<<<(N_NODES * 32 + 255) / 256, 256, 0, stream>>>(pre, out, scaleshift);
}

// Round 7
// 241.753 us; speedup vs baseline: 1.4394x; 1.1045x over previous
//
#include <hip/hip_runtime.h>

// GCN layer: out = ReLU(BN(GCNConv(x) + x@skip_W))
// R7: k_gemm latency fix — full A/B fragment hoist into registers (one latency
//     round-trip), per-block stats partials (no global atomics, no memset),
//     cast+scale merged. Split gather/GEMM structure (R6).

typedef unsigned short ushort;
typedef __bf16 bf16x8 __attribute__((ext_vector_type(8)));
typedef float f32x4 __attribute__((ext_vector_type(4)));

constexpr int N_NODES = 100000;
constexpr int N_PAD   = 100096;                  // 782*128
constexpr int E_EDGES = 1600000;

constexpr int BUCK_SHIFT = 7;                    // 128 nodes per bucket
constexpr int NBUCK   = (N_NODES + 127) / 128;   // 782
constexpr int NBUCK_P = 784;
constexpr int CHUNK   = 4096;
constexpr int NCHUNK  = (E_EDGES + CHUNK - 1) / CHUNK;  // 391
constexpr int SORT_CAP = 4096;

// ws layout (4-byte element offsets)
constexpr size_t OFF_SCALE  = 0;         // 256 floats (scale/shift)
constexpr size_t OFF_DINV   = 256;       // N_PAD floats
constexpr size_t OFF_ROWPTR = 100352;    // N+1 ints (pad to 100128)
constexpr size_t OFF_BASE   = 200480;    // NBUCK+1 ints (pad 800)
constexpr size_t OFF_GHIST  = 201280;    // NCHUNK*NBUCK_P = 306544 ints
constexpr size_t OFF_PART   = OFF_GHIST; // 782*256 floats, aliases gh (dead post-scatter)
constexpr size_t OFF_BINNED = 507824;    // E ints (packed edges; csr in place)
constexpr size_t OFF_XB     = 2107824;   // N_PAD*64 ushort = 3203072 floats
constexpr size_t OFF_U      = 5310896;   // N_PAD*64 ushort
constexpr size_t OFF_PRE    = 8513968;   // N_PAD*128 ushort (bf16 pre-BN)
constexpr size_t OFF_XD     = OFF_PRE;   // xd aliases pre (dead before k_gemm)
constexpr size_t OFF_BT     = 14920112;  // 128*128 ushort = 8192 floats

static __device__ __forceinline__ ushort f2bf(float f) {
    union { float f; unsigned u; } v; v.f = f;
    unsigned r = v.u + 0x7FFFu + ((v.u >> 16) & 1u);  // RNE
    return (ushort)(r >> 16);
}
static __device__ __forceinline__ float bf2f(ushort u) {
    union { unsigned u; float f; } v; v.u = (unsigned)u << 16;
    return v.f;
}

// ---- Bt[n][k] = bf16(B[k][n]), B = [W; skipW] ----
__global__ void k_prep(const float* __restrict__ W, const float* __restrict__ skipW,
                       ushort* __restrict__ Bt) {
    int t = blockIdx.x * 256 + threadIdx.x;
    if (t >= 128 * 128) return;
    int k = t >> 7, n = t & 127;
    float v = (k < 64) ? W[k * 128 + n] : skipW[(k - 64) * 128 + n];
    Bt[n * 128 + k] = f2bf(v);
}

// ---- pass 1: per-chunk histogram over dst buckets ----
__global__ __launch_bounds__(256) void k_hist(const int* __restrict__ col,
                                              int* __restrict__ gh) {
    __shared__ int h[NBUCK_P];
    int c = blockIdx.x, t = threadIdx.x;
    for (int b = t; b < NBUCK_P; b += 256) h[b] = 0;
    __syncthreads();
    int e0 = c * CHUNK;
#pragma unroll
    for (int i = 0; i < CHUNK / 256; ++i) {
        int e = e0 + i * 256 + t;
        if (e < E_EDGES) atomicAdd(&h[col[e] >> BUCK_SHIFT], 1);
    }
    __syncthreads();
    for (int b = t; b < NBUCK_P; b += 256) gh[c * NBUCK_P + b] = h[b];
}

// ---- pass 2a: per-bucket exclusive scan over chunks; bucket totals ----
__global__ __launch_bounds__(512) void k_scan_buckets(int* __restrict__ gh,
                                                      int* __restrict__ base) {
    __shared__ int lds[512];
    int b = blockIdx.x, t = threadIdx.x;
    int v = (t < NCHUNK) ? gh[t * NBUCK_P + b] : 0;
    lds[t] = v;
    __syncthreads();
    int val = v;
#pragma unroll
    for (int off = 1; off < 512; off <<= 1) {
        int add = (t >= off) ? lds[t - off] : 0;
        __syncthreads();
        val += add;
        lds[t] = val;
        __syncthreads();
    }
    if (t < NCHUNK) gh[t * NBUCK_P + b] = val - v;
    if (t == 511) base[b] = val;
}

// ---- pass 2b: exclusive scan of bucket totals -> bucket bases ----
__global__ __launch_bounds__(1024) void k_scan_bases(int* __restrict__ base,
                                                     int* __restrict__ rowptr) {
    __shared__ int lds[1024];
    int t = threadIdx.x;
    int v = (t < NBUCK) ? base[t] : 0;
    lds[t] = v;
    __syncthreads();
    int val = v;
#pragma unroll
    for (int off = 1; off < 1024; off <<= 1) {
        int add = (t >= off) ? lds[t - off] : 0;
        __syncthreads();
        val += add;
        lds[t] = val;
        __syncthreads();
    }
    if (t < NBUCK) base[t] = val - v;
    if (t == 1023) {
        base[NBUCK] = val;
        rowptr[N_NODES] = val;
    }
}

// ---- pass 3: scatter edges into bucket-contiguous array (packed) ----
__global__ __launch_bounds__(256) void k_scatter_bin(const int* __restrict__ row,
                                                     const int* __restrict__ col,
                                                     const int* __restrict__ gh,
                                                     const int* __restrict__ base,
                                                     unsigned int* __restrict__ binned) {
    __shared__ int cur[NBUCK_P];
    int c = blockIdx.x, t = threadIdx.x;
    for (int b = t; b < NBUCK_P; b += 256) {
        int bb = (b < NBUCK) ? base[b] : 0;
        cur[b] = bb + gh[c * NBUCK_P + b];
    }
    __syncthreads();
    int e0 = c * CHUNK;
#pragma unroll
    for (int i = 0; i < CHUNK / 256; ++i) {
        int e = e0 + i * 256 + t;
        if (e < E_EDGES) {
            int d = col[e];
            int s = row[e];
            int p = atomicAdd(&cur[d >> BUCK_SHIFT], 1);
            binned[p] = ((unsigned int)(d & 127) << 17) | (unsigned int)s;
        }
    }
}

// ---- pass 4: per-bucket in-LDS counting sort -> csr, rowptr, dinv ----
__global__ __launch_bounds__(256) void k_sortbucket(unsigned int* __restrict__ binned,
                                                    const int* __restrict__ base,
                                                    int* __restrict__ rowptr,
                                                    float* __restrict__ dinv) {
    __shared__ unsigned int ebuf[SORT_CAP];
    __shared__ int sbuf[SORT_CAP];
    __shared__ int lcnt[128];
    __shared__ int scanb[128];
    __shared__ int lptr[128];
    int b = blockIdx.x, t = threadIdx.x;
    int i0 = base[b], i1 = base[b + 1];
    int cnt = i1 - i0;
    if (cnt > SORT_CAP) cnt = SORT_CAP;
    int n0 = b << BUCK_SHIFT;
    int nn = min(128, N_NODES - n0);

    for (int k = t; k < cnt; k += 256) ebuf[k] = binned[i0 + k];
    if (t < 128) lcnt[t] = 0;
    __syncthreads();
    for (int k = t; k < cnt; k += 256) atomicAdd(&lcnt[ebuf[k] >> 17], 1);
    __syncthreads();

    int myc = (t < 128) ? lcnt[t] : 0;
    if (t < 128) scanb[t] = myc;
    __syncthreads();
    int val = myc;
#pragma unroll
    for (int off = 1; off < 128; off <<= 1) {
        int add = (t < 128 && t >= off) ? scanb[t - off] : 0;
        __syncthreads();
        if (t < 128) {
            val += add;
            scanb[t] = val;
        }
        __syncthreads();
    }
    if (t < 128) {
        int excl = val - myc;
        lptr[t] = excl;
        if (t < nn) {
            rowptr[n0 + t] = i0 + excl;
            dinv[n0 + t] = rsqrtf((float)myc + 1.0f);  // +1 self loop
        }
    }
    __syncthreads();
    for (int k = t; k < cnt; k += 256) {
        unsigned int e = ebuf[k];
        int j = (int)(e >> 17);
        int p = atomicAdd(&lptr[j], 1);
        sbuf[p] = (int)(e & 0x1FFFF);
    }
    __syncthreads();
    for (int k = t; k < cnt; k += 256) binned[i0 + k] = (unsigned int)sbuf[k];
}

// ---- xb = bf16(x), xd = bf16(x*dinv) in one pass (after sort: dinv ready) ----
__global__ void k_cast_scale(const float* __restrict__ x, const float* __restrict__ dinv,
                             ushort* __restrict__ xb, ushort* __restrict__ xd) {
    int t = blockIdx.x * blockDim.x + threadIdx.x;
    if (t >= N_PAD * 16) return;
    int c = t >> 4;
    ushort4 b = {0, 0, 0, 0};
    ushort4 o = {0, 0, 0, 0};
    if (c < N_NODES) {
        float d = dinv[c];
        float4 v = ((const float4*)x)[t];
        b.x = f2bf(v.x); b.y = f2bf(v.y); b.z = f2bf(v.z); b.w = f2bf(v.w);
        o.x = f2bf(v.x * d); o.y = f2bf(v.y * d);
        o.z = f2bf(v.z * d); o.w = f2bf(v.w * d);
    }
    ((ushort4*)xb)[t] = b;
    ((ushort4*)xd)[t] = o;
}

// ---- aggregation: 16 lanes per node; unroll-4 batched independent gathers ----
// u[c] = bf16( dinv[c] * ( xd[c] + sum_{r->c} xd[r] ) )
__global__ __launch_bounds__(256) void k_agg(const ushort* __restrict__ xd,
                                             const float* __restrict__ dinv,
                                             const int* __restrict__ rowptr,
                                             const unsigned int* __restrict__ csr,
                                             ushort* __restrict__ u) {
    int t = blockIdx.x * blockDim.x + threadIdx.x;
    if (t >= N_PAD * 16) return;
    int c = t >> 4;
    int q = t & 15;
    if (c >= N_NODES) {
        ushort4 z = {0, 0, 0, 0};
        ((ushort4*)u)[t] = z;
        return;
    }
    float dc = dinv[c];
    ushort4 xv = ((const ushort4*)xd)[t];
    float4 acc;
    acc.x = bf2f(xv.x); acc.y = bf2f(xv.y);
    acc.z = bf2f(xv.z); acc.w = bf2f(xv.w);
    int i0 = rowptr[c], i1 = rowptr[c + 1];
    int i = i0;
    for (; i + 4 <= i1; i += 4) {
        int s0 = (int)csr[i];
        int s1 = (int)csr[i + 1];
        int s2 = (int)csr[i + 2];
        int s3 = (int)csr[i + 3];
        ushort4 v0 = ((const ushort4*)xd)[s0 * 16 + q];
        ushort4 v1 = ((const ushort4*)xd)[s1 * 16 + q];
        ushort4 v2 = ((const ushort4*)xd)[s2 * 16 + q];
        ushort4 v3 = ((const ushort4*)xd)[s3 * 16 + q];
        acc.x += bf2f(v0.x) + bf2f(v1.x) + bf2f(v2.x) + bf2f(v3.x);
        acc.y += bf2f(v0.y) + bf2f(v1.y) + bf2f(v2.y) + bf2f(v3.y);
        acc.z += bf2f(v0.z) + bf2f(v1.z) + bf2f(v2.z) + bf2f(v3.z);
        acc.w += bf2f(v0.w) + bf2f(v1.w) + bf2f(v2.w) + bf2f(v3.w);
    }
    for (; i < i1; ++i) {
        int s = (int)csr[i];
        ushort4 v = ((const ushort4*)xd)[s * 16 + q];
        acc.x += bf2f(v.x); acc.y += bf2f(v.y);
        acc.z += bf2f(v.z); acc.w += bf2f(v.w);
    }
    ushort4 o;
    o.x = f2bf(acc.x * dc); o.y = f2bf(acc.y * dc);
    o.z = f2bf(acc.z * dc); o.w = f2bf(acc.w * dc);
    ((ushort4*)u)[t] = o;
}

// ---- MFMA GEMM: pre = [u|xb] @ Bt^T + bias (bf16 out); per-block stat partials ----
// ALL 32 fragment loads hoisted into registers before the MFMA block: one
// latency round-trip per wave (VGPR ~200 by design). No global atomics.
__global__ __launch_bounds__(256) void k_gemm(const ushort* __restrict__ u,
                                              const ushort* __restrict__ xb,
                                              const ushort* __restrict__ Bt,
                                              const float* __restrict__ bias,
                                              ushort* __restrict__ pre,
                                              float* __restrict__ partial) {
    __shared__ float sred[128];
    __shared__ float qred[128];
    int tid = threadIdx.x;
    int wave = tid >> 6, lane = tid & 63;
    int wm = wave >> 1, wn = wave & 1;
    int l15 = lane & 15, quad = lane >> 4;
    int row0 = blockIdx.x * 128 + wm * 64;
    int col0 = wn * 64;

    if (tid < 128) { sred[tid] = 0.f; qred[tid] = 0.f; }
    __syncthreads();

    // hoisted fragment loads: af[kc][im], bf_[kc][jn]
    bf16x8 af[4][4], bf_[4][4];
#pragma unroll
    for (int kc = 0; kc < 4; ++kc) {
        const ushort* abase = (kc < 2) ? u : xb;
        int ko = (kc & 1) * 32 + quad * 8;
#pragma unroll
        for (int im = 0; im < 4; ++im)
            af[kc][im] = *(const bf16x8*)&abase[(size_t)(row0 + im * 16 + l15) * 64 + ko];
#pragma unroll
        for (int jn = 0; jn < 4; ++jn)
            bf_[kc][jn] = *(const bf16x8*)&Bt[(size_t)(col0 + jn * 16 + l15) * 128 + kc * 32 + quad * 8];
    }

    f32x4 acc[4][4];
#pragma unroll
    for (int a = 0; a < 4; ++a)
#pragma unroll
        for (int b = 0; b < 4; ++b) acc[a][b] = (f32x4){0.f, 0.f, 0.f, 0.f};

#pragma unroll
    for (int kc = 0; kc < 4; ++kc)
#pragma unroll
        for (int im = 0; im < 4; ++im)
#pragma unroll
            for (int jn = 0; jn < 4; ++jn)
                acc[im][jn] = __builtin_amdgcn_mfma_f32_16x16x32_bf16(
                    af[kc][im], bf_[kc][jn], acc[im][jn], 0, 0, 0);

    int coln[4];
    float bi[4];
#pragma unroll
    for (int jn = 0; jn < 4; ++jn) {
        coln[jn] = col0 + jn * 16 + l15;
        bi[jn] = bias[coln[jn]];
    }
    float lsum[4] = {0.f, 0.f, 0.f, 0.f};
    float lsq[4]  = {0.f, 0.f, 0.f, 0.f};
#pragma unroll
    for (int im = 0; im < 4; ++im) {
        int rbase = row0 + im * 16 + quad * 4;
#pragma unroll
        for (int r = 0; r < 4; ++r) {
            int rowi = rbase + r;
            if (rowi < N_NODES) {
#pragma unroll
                for (int jn = 0; jn < 4; ++jn) {
                    float v = acc[im][jn][r] + bi[jn];
                    pre[(size_t)rowi * 128 + coln[jn]] = f2bf(v);
                    lsum[jn] += v;
                    lsq[jn]  += v * v;
                }
            }
        }
    }
#pragma unroll
    for (int jn = 0; jn < 4; ++jn) {
        atomicAdd(&sred[coln[jn]], lsum[jn]);
        atomicAdd(&qred[coln[jn]], lsq[jn]);
    }
    __syncthreads();
    if (tid < 128) {
        partial[(size_t)blockIdx.x * 256 + tid]       = sred[tid];
        partial[(size_t)blockIdx.x * 256 + 128 + tid] = qred[tid];
    }
}

// ---- reduce 782 partials -> scale/shift (one block per output column) ----
__global__ __launch_bounds__(256) void k_reduce(const float* __restrict__ partial,
                                                const float* __restrict__ gamma,
                                                const float* __restrict__ beta,
                                                float* __restrict__ scaleshift) {
    __shared__ float ls[256], lq[256];
    int j = blockIdx.x;   // 0..127
    int t = threadIdx.x;
    float s = 0.f, q = 0.f;
    for (int p = t; p < NBUCK; p += 256) {
        s += partial[(size_t)p * 256 + j];
        q += partial[(size_t)p * 256 + 128 + j];
    }
    ls[t] = s; lq[t] = q;
    __syncthreads();
#pragma unroll
    for (int off = 128; off > 0; off >>= 1) {
        if (t < off) { ls[t] += ls[t + off]; lq[t] += lq[t + off]; }
        __syncthreads();
    }
    if (t == 0) {
        float mean = ls[0] * (1.0f / N_NODES);
        float var  = lq[0] * (1.0f / N_NODES) - mean * mean;
        float sc   = gamma[j] * rsqrtf(var + 1e-5f);
        scaleshift[j]       = sc;
        scaleshift[128 + j] = beta[j] - mean * sc;
    }
}

// read bf16 pre, write fp32 out
__global__ void k_apply(const ushort* __restrict__ pre, float* __restrict__ out,
                        const float* __restrict__ scaleshift) {
    int t = blockIdx.x * blockDim.x + threadIdx.x;
    if (t >= N_NODES * 32) return;
    int j4 = t & 31;
    ushort4 p = ((const ushort4*)pre)[t];
    float4 sc = ((const float4*)scaleshift)[j4];
    float4 sh = ((const float4*)(scaleshift + 128))[j4];
    float4 v;
    v.x = fmaxf(fmaf(bf2f(p.x), sc.x, sh.x), 0.f);
    v.y = fmaxf(fmaf(bf2f(p.y), sc.y, sh.y), 0.f);
    v.z = fmaxf(fmaf(bf2f(p.z), sc.z, sh.z), 0.f);
    v.w = fmaxf(fmaf(bf2f(p.w), sc.w, sh.w), 0.f);
    ((float4*)out)[t] = v;
}

extern "C" void kernel_launch(void* const* d_in, const int* in_sizes, int n_in,
                              void* d_out, int out_size, void* d_ws, size_t ws_size,
                              hipStream_t stream) {
    const float* x      = (const float*)d_in[0];
    const int*   eidx   = (const int*)d_in[1];
    const float* W      = (const float*)d_in[2];
    const float* bias   = (const float*)d_in[3];
    const float* skipW  = (const float*)d_in[4];
    const float* gamma  = (const float*)d_in[5];
    const float* beta   = (const float*)d_in[6];
    float* out = (float*)d_out;
    float* ws  = (float*)d_ws;

    const int* row = eidx;
    const int* col = eidx + E_EDGES;

    float* scaleshift = ws + OFF_SCALE;
    float* dinv       = ws + OFF_DINV;
    int*   rowptr     = (int*)(ws + OFF_ROWPTR);
    int*   base       = (int*)(ws + OFF_BASE);
    int*   gh         = (int*)(ws + OFF_GHIST);
    float* partial    = ws + OFF_PART;            // aliases gh (dead after scatter)
    unsigned int* binned = (unsigned int*)(ws + OFF_BINNED);
    ushort* xb        = (ushort*)(ws + OFF_XB);
    ushort* u         = (ushort*)(ws + OFF_U);
    ushort* xd        = (ushort*)(ws + OFF_XD);   // aliases pre (dead by k_gemm)
    ushort* pre       = (ushort*)(ws + OFF_PRE);
    ushort* Bt        = (ushort*)(ws + OFF_BT);

    k_prep<<<64, 256, 0, stream>>>(W, skipW, Bt);
    k_hist<<<NCHUNK, 256, 0, stream>>>(col, gh);
    k_scan_buckets<<<NBUCK, 512, 0, stream>>>(gh, base);
    k_scan_bases<<<1, 1024, 0, stream>>>(base, rowptr);
    k_scatter_bin<<<NCHUNK, 256, 0, stream>>>(row, col, gh, base, binned);
    k_sortbucket<<<NBUCK, 256, 0, stream>>>(binned, base, rowptr, dinv);
    k_cast_scale<<<(N_PAD * 16 + 255) / 256, 256, 0, stream>>>(x, dinv, xb, xd);
    k_agg<<<(N_PAD * 16 + 255) / 256, 256, 0, stream>>>(xd, dinv, rowptr, binned, u);
    k_gemm<<<NBUCK, 256, 0, stream>>>(u, xb, Bt, bias, pre, partial);
    k_reduce<<<128, 256, 0, stream>>>(partial, gamma, beta, scaleshift);
    k_apply<<<(N_NODES * 32 + 255) / 256, 256, 0, stream>>>(pre, out, scaleshift);
}

// Round 8
// 230.033 us; speedup vs baseline: 1.5127x; 1.0509x over previous
//
#include <hip/hip_runtime.h>

// GCN layer: out = ReLU(BN(GCNConv(x) + x@skip_W))
// R8: fp8(e4m3) gather operand xd8 (64B/row = 1 line/edge, halves gather
//     bytes), unroll-8 gather, cast/scale fused into sortbucket.
//     GEMM stays bf16 MFMA with full fragment hoist (R7).

typedef unsigned short ushort;
typedef __bf16 bf16x8 __attribute__((ext_vector_type(8)));
typedef float f32x4 __attribute__((ext_vector_type(4)));
typedef float f32x2 __attribute__((ext_vector_type(2)));

constexpr int N_NODES = 100000;
constexpr int N_PAD   = 100096;                  // 782*128
constexpr int E_EDGES = 1600000;

constexpr int BUCK_SHIFT = 7;                    // 128 nodes per bucket
constexpr int NBUCK   = (N_NODES + 127) / 128;   // 782
constexpr int NBUCK_P = 784;
constexpr int CHUNK   = 4096;
constexpr int NCHUNK  = (E_EDGES + CHUNK - 1) / CHUNK;  // 391
constexpr int SORT_CAP = 4096;

// ws layout (4-byte element offsets)
constexpr size_t OFF_SCALE  = 0;         // 256 floats (scale/shift)
constexpr size_t OFF_DINV   = 256;       // N_PAD floats
constexpr size_t OFF_ROWPTR = 100352;    // N+1 ints
constexpr size_t OFF_BASE   = 200480;    // NBUCK+1 ints (pad 800)
constexpr size_t OFF_GHIST  = 201280;    // NCHUNK*NBUCK_P = 306544 ints
constexpr size_t OFF_PART   = OFF_GHIST; // 782*256 floats, aliases gh (dead post-scatter)
constexpr size_t OFF_BINNED = 507824;    // E ints (packed edges; csr in place)
constexpr size_t OFF_XB     = 2107824;   // N_PAD*64 ushort = 3203072 floats
constexpr size_t OFF_U      = 5310896;   // N_PAD*64 ushort
constexpr size_t OFF_PRE    = 8513968;   // N_PAD*128 ushort (bf16 pre-BN)
constexpr size_t OFF_XD8    = OFF_PRE;   // N_PAD*16 uints, aliases pre (dead by k_gemm)
constexpr size_t OFF_BT     = 14920112;  // 128*128 ushort = 8192 floats

static __device__ __forceinline__ ushort f2bf(float f) {
    union { float f; unsigned u; } v; v.f = f;
    unsigned r = v.u + 0x7FFFu + ((v.u >> 16) & 1u);  // RNE
    return (ushort)(r >> 16);
}
static __device__ __forceinline__ float bf2f(ushort u) {
    union { unsigned u; float f; } v; v.u = (unsigned)u << 16;
    return v.f;
}
static __device__ __forceinline__ unsigned pack_fp8x4(float a, float b, float c, float d) {
    int r = 0;
    r = __builtin_amdgcn_cvt_pk_fp8_f32(a, b, r, false);
    r = __builtin_amdgcn_cvt_pk_fp8_f32(c, d, r, true);
    return (unsigned)r;
}

// ---- Bt[n][k] = bf16(B[k][n]), B = [W; skipW] ----
__global__ void k_prep(const float* __restrict__ W, const float* __restrict__ skipW,
                       ushort* __restrict__ Bt) {
    int t = blockIdx.x * 256 + threadIdx.x;
    if (t >= 128 * 128) return;
    int k = t >> 7, n = t & 127;
    float v = (k < 64) ? W[k * 128 + n] : skipW[(k - 64) * 128 + n];
    Bt[n * 128 + k] = f2bf(v);
}

// ---- pass 1: per-chunk histogram over dst buckets ----
__global__ __launch_bounds__(256) void k_hist(const int* __restrict__ col,
                                              int* __restrict__ gh) {
    __shared__ int h[NBUCK_P];
    int c = blockIdx.x, t = threadIdx.x;
    for (int b = t; b < NBUCK_P; b += 256) h[b] = 0;
    __syncthreads();
    int e0 = c * CHUNK;
#pragma unroll
    for (int i = 0; i < CHUNK / 256; ++i) {
        int e = e0 + i * 256 + t;
        if (e < E_EDGES) atomicAdd(&h[col[e] >> BUCK_SHIFT], 1);
    }
    __syncthreads();
    for (int b = t; b < NBUCK_P; b += 256) gh[c * NBUCK_P + b] = h[b];
}

// ---- pass 2a: per-bucket exclusive scan over chunks; bucket totals ----
__global__ __launch_bounds__(512) void k_scan_buckets(int* __restrict__ gh,
                                                      int* __restrict__ base) {
    __shared__ int lds[512];
    int b = blockIdx.x, t = threadIdx.x;
    int v = (t < NCHUNK) ? gh[t * NBUCK_P + b] : 0;
    lds[t] = v;
    __syncthreads();
    int val = v;
#pragma unroll
    for (int off = 1; off < 512; off <<= 1) {
        int add = (t >= off) ? lds[t - off] : 0;
        __syncthreads();
        val += add;
        lds[t] = val;
        __syncthreads();
    }
    if (t < NCHUNK) gh[t * NBUCK_P + b] = val - v;
    if (t == 511) base[b] = val;
}

// ---- pass 2b: exclusive scan of bucket totals -> bucket bases ----
__global__ __launch_bounds__(1024) void k_scan_bases(int* __restrict__ base,
                                                     int* __restrict__ rowptr) {
    __shared__ int lds[1024];
    int t = threadIdx.x;
    int v = (t < NBUCK) ? base[t] : 0;
    lds[t] = v;
    __syncthreads();
    int val = v;
#pragma unroll
    for (int off = 1; off < 1024; off <<= 1) {
        int add = (t >= off) ? lds[t - off] : 0;
        __syncthreads();
        val += add;
        lds[t] = val;
        __syncthreads();
    }
    if (t < NBUCK) base[t] = val - v;
    if (t == 1023) {
        base[NBUCK] = val;
        rowptr[N_NODES] = val;
    }
}

// ---- pass 3: scatter edges into bucket-contiguous array (packed) ----
__global__ __launch_bounds__(256) void k_scatter_bin(const int* __restrict__ row,
                                                     const int* __restrict__ col,
                                                     const int* __restrict__ gh,
                                                     const int* __restrict__ base,
                                                     unsigned int* __restrict__ binned) {
    __shared__ int cur[NBUCK_P];
    int c = blockIdx.x, t = threadIdx.x;
    for (int b = t; b < NBUCK_P; b += 256) {
        int bb = (b < NBUCK) ? base[b] : 0;
        cur[b] = bb + gh[c * NBUCK_P + b];
    }
    __syncthreads();
    int e0 = c * CHUNK;
#pragma unroll
    for (int i = 0; i < CHUNK / 256; ++i) {
        int e = e0 + i * 256 + t;
        if (e < E_EDGES) {
            int d = col[e];
            int s = row[e];
            int p = atomicAdd(&cur[d >> BUCK_SHIFT], 1);
            binned[p] = ((unsigned int)(d & 127) << 17) | (unsigned int)s;
        }
    }
}

// ---- pass 4: per-bucket counting sort -> csr, rowptr, dinv; fused cast:
//      xb = bf16(x), xd8 = fp8(x*dinv) for this bucket's 128 nodes ----
__global__ __launch_bounds__(256) void k_sortbucket(unsigned int* __restrict__ binned,
                                                    const int* __restrict__ base,
                                                    int* __restrict__ rowptr,
                                                    float* __restrict__ dinv,
                                                    const float* __restrict__ x,
                                                    ushort* __restrict__ xb,
                                                    unsigned* __restrict__ xd8) {
    __shared__ unsigned int ebuf[SORT_CAP];
    __shared__ int sbuf[SORT_CAP];
    __shared__ int lcnt[128];
    __shared__ int scanb[128];
    __shared__ int lptr[128];
    __shared__ float ldinv[128];
    int b = blockIdx.x, t = threadIdx.x;
    int i0 = base[b], i1 = base[b + 1];
    int cnt = i1 - i0;
    if (cnt > SORT_CAP) cnt = SORT_CAP;
    int n0 = b << BUCK_SHIFT;
    int nn = min(128, N_NODES - n0);

    for (int k = t; k < cnt; k += 256) ebuf[k] = binned[i0 + k];
    if (t < 128) lcnt[t] = 0;
    __syncthreads();
    for (int k = t; k < cnt; k += 256) atomicAdd(&lcnt[ebuf[k] >> 17], 1);
    __syncthreads();

    int myc = (t < 128) ? lcnt[t] : 0;
    if (t < 128) scanb[t] = myc;
    __syncthreads();
    int val = myc;
#pragma unroll
    for (int off = 1; off < 128; off <<= 1) {
        int add = (t < 128 && t >= off) ? scanb[t - off] : 0;
        __syncthreads();
        if (t < 128) {
            val += add;
            scanb[t] = val;
        }
        __syncthreads();
    }
    if (t < 128) {
        int excl = val - myc;
        lptr[t] = excl;
        float dv = rsqrtf((float)myc + 1.0f);  // +1 self loop
        ldinv[t] = dv;
        if (t < nn) {
            rowptr[n0 + t] = i0 + excl;
            dinv[n0 + t] = dv;
        }
    }
    __syncthreads();
    for (int k = t; k < cnt; k += 256) {
        unsigned int e = ebuf[k];
        int j = (int)(e >> 17);
        int p = atomicAdd(&lptr[j], 1);
        sbuf[p] = (int)(e & 0x1FFFF);
    }
    __syncthreads();
    for (int k = t; k < cnt; k += 256) binned[i0 + k] = (unsigned int)sbuf[k];

    // fused cast: this bucket's 128 node rows -> xb (bf16), xd8 (fp8*dinv)
#pragma unroll
    for (int it = 0; it < 8; ++it) {
        int idx = it * 256 + t;          // 0..2047
        int nl = idx >> 4, q = idx & 15;
        int c = n0 + nl;
        ushort4 bb = {0, 0, 0, 0};
        unsigned w8 = 0;
        if (nl < nn) {
            float4 v = ((const float4*)x)[(size_t)c * 16 + q];
            bb.x = f2bf(v.x); bb.y = f2bf(v.y); bb.z = f2bf(v.z); bb.w = f2bf(v.w);
            float d = ldinv[nl];
            w8 = pack_fp8x4(v.x * d, v.y * d, v.z * d, v.w * d);
        }
        ((ushort4*)xb)[(size_t)c * 16 + q] = bb;
        xd8[(size_t)c * 16 + q] = w8;
    }
}

// ---- aggregation: 16 lanes per node; fp8 gather (1 line/edge), unroll-8 ----
// u[c] = bf16( dinv[c] * sum(xd8[c], xd8[r]...) ),  xd8 = fp8(x*dinv)
__global__ __launch_bounds__(256) void k_agg(const unsigned* __restrict__ xd8,
                                             const float* __restrict__ dinv,
                                             const int* __restrict__ rowptr,
                                             const unsigned int* __restrict__ csr,
                                             ushort* __restrict__ u) {
    int t = blockIdx.x * blockDim.x + threadIdx.x;
    if (t >= N_PAD * 16) return;
    int c = t >> 4;
    int q = t & 15;
    if (c >= N_NODES) {
        ushort4 z = {0, 0, 0, 0};
        ((ushort4*)u)[t] = z;
        return;
    }
    float dc = dinv[c];
    float4 acc;
    {
        unsigned w = xd8[t];
        f32x2 lo = __builtin_amdgcn_cvt_pk_f32_fp8((int)w, false);
        f32x2 hi = __builtin_amdgcn_cvt_pk_f32_fp8((int)w, true);
        acc.x = lo.x; acc.y = lo.y; acc.z = hi.x; acc.w = hi.y;
    }
    int i0 = rowptr[c], i1 = rowptr[c + 1];
    int i = i0;
    for (; i + 8 <= i1; i += 8) {
        int s[8];
#pragma unroll
        for (int k = 0; k < 8; ++k) s[k] = (int)csr[i + k];
        unsigned w[8];
#pragma unroll
        for (int k = 0; k < 8; ++k) w[k] = xd8[s[k] * 16 + q];
#pragma unroll
        for (int k = 0; k < 8; ++k) {
            f32x2 lo = __builtin_amdgcn_cvt_pk_f32_fp8((int)w[k], false);
            f32x2 hi = __builtin_amdgcn_cvt_pk_f32_fp8((int)w[k], true);
            acc.x += lo.x; acc.y += lo.y; acc.z += hi.x; acc.w += hi.y;
        }
    }
    for (; i < i1; ++i) {
        unsigned w = xd8[(int)csr[i] * 16 + q];
        f32x2 lo = __builtin_amdgcn_cvt_pk_f32_fp8((int)w, false);
        f32x2 hi = __builtin_amdgcn_cvt_pk_f32_fp8((int)w, true);
        acc.x += lo.x; acc.y += lo.y; acc.z += hi.x; acc.w += hi.y;
    }
    ushort4 o;
    o.x = f2bf(acc.x * dc); o.y = f2bf(acc.y * dc);
    o.z = f2bf(acc.z * dc); o.w = f2bf(acc.w * dc);
    ((ushort4*)u)[t] = o;
}

// ---- MFMA GEMM: pre = [u|xb] @ Bt^T + bias (bf16 out); per-block stat partials ----
__global__ __launch_bounds__(256) void k_gemm(const ushort* __restrict__ u,
                                              const ushort* __restrict__ xb,
                                              const ushort* __restrict__ Bt,
                                              const float* __restrict__ bias,
                                              ushort* __restrict__ pre,
                                              float* __restrict__ partial) {
    __shared__ float sred[128];
    __shared__ float qred[128];
    int tid = threadIdx.x;
    int wave = tid >> 6, lane = tid & 63;
    int wm = wave >> 1, wn = wave & 1;
    int l15 = lane & 15, quad = lane >> 4;
    int row0 = blockIdx.x * 128 + wm * 64;
    int col0 = wn * 64;

    if (tid < 128) { sred[tid] = 0.f; qred[tid] = 0.f; }
    __syncthreads();

    bf16x8 af[4][4], bf_[4][4];
#pragma unroll
    for (int kc = 0; kc < 4; ++kc) {
        const ushort* abase = (kc < 2) ? u : xb;
        int ko = (kc & 1) * 32 + quad * 8;
#pragma unroll
        for (int im = 0; im < 4; ++im)
            af[kc][im] = *(const bf16x8*)&abase[(size_t)(row0 + im * 16 + l15) * 64 + ko];
#pragma unroll
        for (int jn = 0; jn < 4; ++jn)
            bf_[kc][jn] = *(const bf16x8*)&Bt[(size_t)(col0 + jn * 16 + l15) * 128 + kc * 32 + quad * 8];
    }

    f32x4 acc[4][4];
#pragma unroll
    for (int a = 0; a < 4; ++a)
#pragma unroll
        for (int b = 0; b < 4; ++b) acc[a][b] = (f32x4){0.f, 0.f, 0.f, 0.f};

#pragma unroll
    for (int kc = 0; kc < 4; ++kc)
#pragma unroll
        for (int im = 0; im < 4; ++im)
#pragma unroll
            for (int jn = 0; jn < 4; ++jn)
                acc[im][jn] = __builtin_amdgcn_mfma_f32_16x16x32_bf16(
                    af[kc][im], bf_[kc][jn], acc[im][jn], 0, 0, 0);

    int coln[4];
    float bi[4];
#pragma unroll
    for (int jn = 0; jn < 4; ++jn) {
        coln[jn] = col0 + jn * 16 + l15;
        bi[jn] = bias[coln[jn]];
    }
    float lsum[4] = {0.f, 0.f, 0.f, 0.f};
    float lsq[4]  = {0.f, 0.f, 0.f, 0.f};
#pragma unroll
    for (int im = 0; im < 4; ++im) {
        int rbase = row0 + im * 16 + quad * 4;
#pragma unroll
        for (int r = 0; r < 4; ++r) {
            int rowi = rbase + r;
            if (rowi < N_NODES) {
#pragma unroll
                for (int jn = 0; jn < 4; ++jn) {
                    float v = acc[im][jn][r] + bi[jn];
                    pre[(size_t)rowi * 128 + coln[jn]] = f2bf(v);
                    lsum[jn] += v;
                    lsq[jn]  += v * v;
                }
            }
        }
    }
#pragma unroll
    for (int jn = 0; jn < 4; ++jn) {
        atomicAdd(&sred[coln[jn]], lsum[jn]);
        atomicAdd(&qred[coln[jn]], lsq[jn]);
    }
    __syncthreads();
    if (tid < 128) {
        partial[(size_t)blockIdx.x * 256 + tid]       = sred[tid];
        partial[(size_t)blockIdx.x * 256 + 128 + tid] = qred[tid];
    }
}

// ---- reduce 782 partials -> scale/shift (one block per output column) ----
__global__ __launch_bounds__(256) void k_reduce(const float* __restrict__ partial,
                                                const float* __restrict__ gamma,
                                                const float* __restrict__ beta,
                                                float* __restrict__ scaleshift) {
    __shared__ float ls[256], lq[256];
    int j = blockIdx.x;   // 0..127
    int t = threadIdx.x;
    float s = 0.f, q = 0.f;
    for (int p = t; p < NBUCK; p += 256) {
        s += partial[(size_t)p * 256 + j];
        q += partial[(size_t)p * 256 + 128 + j];
    }
    ls[t] = s; lq[t] = q;
    __syncthreads();
#pragma unroll
    for (int off = 128; off > 0; off >>= 1) {
        if (t < off) { ls[t] += ls[t + off]; lq[t] += lq[t + off]; }
        __syncthreads();
    }
    if (t == 0) {
        float mean = ls[0] * (1.0f / N_NODES);
        float var  = lq[0] * (1.0f / N_NODES) - mean * mean;
        float sc   = gamma[j] * rsqrtf(var + 1e-5f);
        scaleshift[j]       = sc;
        scaleshift[128 + j] = beta[j] - mean * sc;
    }
}

// read bf16 pre, write fp32 out
__global__ void k_apply(const ushort* __restrict__ pre, float* __restrict__ out,
                        const float* __restrict__ scaleshift) {
    int t = blockIdx.x * blockDim.x + threadIdx.x;
    if (t >= N_NODES * 32) return;
    int j4 = t & 31;
    ushort4 p = ((const ushort4*)pre)[t];
    float4 sc = ((const float4*)scaleshift)[j4];
    float4 sh = ((const float4*)(scaleshift + 128))[j4];
    float4 v;
    v.x = fmaxf(fmaf(bf2f(p.x), sc.x, sh.x), 0.f);
    v.y = fmaxf(fmaf(bf2f(p.y), sc.y, sh.y), 0.f);
    v.z = fmaxf(fmaf(bf2f(p.z), sc.z, sh.z), 0.f);
    v.w = fmaxf(fmaf(bf2f(p.w), sc.w, sh.w), 0.f);
    ((float4*)out)[t] = v;
}

extern "C" void kernel_launch(void* const* d_in, const int* in_sizes, int n_in,
                              void* d_out, int out_size, void* d_ws, size_t ws_size,
                              hipStream_t stream) {
    const float* x      = (const float*)d_in[0];
    const int*   eidx   = (const int*)d_in[1];
    const float* W      = (const float*)d_in[2];
    const float* bias   = (const float*)d_in[3];
    const float* skipW  = (const float*)d_in[4];
    const float* gamma  = (const float*)d_in[5];
    const float* beta   = (const float*)d_in[6];
    float* out = (float*)d_out;
    float* ws  = (float*)d_ws;

    const int* row = eidx;
    const int* col = eidx + E_EDGES;

    float* scaleshift = ws + OFF_SCALE;
    float* dinv       = ws + OFF_DINV;
    int*   rowptr     = (int*)(ws + OFF_ROWPTR);
    int*   base       = (int*)(ws + OFF_BASE);
    int*   gh         = (int*)(ws + OFF_GHIST);
    float* partial    = ws + OFF_PART;            // aliases gh (dead after scatter)
    unsigned int* binned = (unsigned int*)(ws + OFF_BINNED);
    ushort* xb        = (ushort*)(ws + OFF_XB);
    ushort* u         = (ushort*)(ws + OFF_U);
    unsigned* xd8     = (unsigned*)(ws + OFF_XD8);  // aliases pre (dead by k_gemm)
    ushort* pre       = (ushort*)(ws + OFF_PRE);
    ushort* Bt        = (ushort*)(ws + OFF_BT);

    k_prep<<<64, 256, 0, stream>>>(W, skipW, Bt);
    k_hist<<<NCHUNK, 256, 0, stream>>>(col, gh);
    k_scan_buckets<<<NBUCK, 512, 0, stream>>>(gh, base);
    k_scan_bases<<<1, 1024, 0, stream>>>(base, rowptr);
    k_scatter_bin<<<NCHUNK, 256, 0, stream>>>(row, col, gh, base, binned);
    k_sortbucket<<<NBUCK, 256, 0, stream>>>(binned, base, rowptr, dinv, x, xb, xd8);
    k_agg<<<(N_PAD * 16 + 255) / 256, 256, 0, stream>>>(xd8, dinv, rowptr, binned, u);
    k_gemm<<<NBUCK, 256, 0, stream>>>(u, xb, Bt, bias, pre, partial);
    k_reduce<<<128, 256, 0, stream>>>(partial, gamma, beta, scaleshift);
    k_apply<<<(N_NODES * 32 + 255) / 256, 256, 0, stream>>>(pre, out, scaleshift);
}